// Round 3
// baseline (288.810 us; speedup 1.0000x reference)
//
#include <hip/hip_runtime.h>
#include <hip/hip_bf16.h>

#define NB 64
#define NN 512
#define ED 128
#define NF 128
#define PAD_ID 49999

typedef __hip_bfloat16 bf16;

__device__ __forceinline__ float wave_max(float v) {
#pragma unroll
    for (int off = 32; off; off >>= 1) v = fmaxf(v, __shfl_xor(v, off));
    return v;
}
__device__ __forceinline__ float wave_sum(float v) {
#pragma unroll
    for (int off = 32; off; off >>= 1) v += __shfl_xor(v, off);
    return v;
}

// ---------------- Kernel 1: h = emb[doc] @ W, e_src, e_dst ----------------
__global__ __launch_bounds__(256) void k_h(
    const int* __restrict__ doc, const float* __restrict__ emb,
    const float* __restrict__ W, const float* __restrict__ a_src,
    const float* __restrict__ a_dst, float* __restrict__ h,
    float* __restrict__ esrc, float* __restrict__ edst)
{
    __shared__ float wl[16][129];   // 16 tokens x 128, padded (bank spread)
    const int tid = threadIdx.x;
    const int t0 = blockIdx.x * 16;

    // stage gathered word embeddings: 16 tokens * 32 float4 = 512 float4
#pragma unroll
    for (int k = 0; k < 2; ++k) {
        int idx = tid + k * 256;
        int tok = idx >> 5;
        int e4  = (idx & 31) << 2;
        int d   = doc[t0 + tok];
        const float4 v = *(const float4*)(emb + (size_t)d * ED + e4);
        wl[tok][e4 + 0] = v.x; wl[tok][e4 + 1] = v.y;
        wl[tok][e4 + 2] = v.z; wl[tok][e4 + 3] = v.w;
    }
    __syncthreads();

    const int tok = tid >> 4;        // 0..15
    const int fg  = tid & 15;        // 0..15
    const int f0  = fg << 2;         // feats [f0, f0+4)
    const int f1  = 64 + f0;         // feats [f1, f1+4)

    float a0[4] = {0.f,0.f,0.f,0.f}, a1[4] = {0.f,0.f,0.f,0.f};
#pragma unroll 4
    for (int e = 0; e < 128; ++e) {
        float w = wl[tok][e];
        const float4 wa = *(const float4*)(W + e * NF + f0);
        const float4 wb = *(const float4*)(W + e * NF + f1);
        a0[0] = fmaf(w, wa.x, a0[0]); a0[1] = fmaf(w, wa.y, a0[1]);
        a0[2] = fmaf(w, wa.z, a0[2]); a0[3] = fmaf(w, wa.w, a0[3]);
        a1[0] = fmaf(w, wb.x, a1[0]); a1[1] = fmaf(w, wb.y, a1[1]);
        a1[2] = fmaf(w, wb.z, a1[2]); a1[3] = fmaf(w, wb.w, a1[3]);
    }

    const int t = t0 + tok;
    *(float4*)(h + (size_t)t * NF + f0) = make_float4(a0[0], a0[1], a0[2], a0[3]);
    *(float4*)(h + (size_t)t * NF + f1) = make_float4(a1[0], a1[1], a1[2], a1[3]);

    const float4 as0 = *(const float4*)(a_src + f0);
    const float4 as1 = *(const float4*)(a_src + f1);
    const float4 ad0 = *(const float4*)(a_dst + f0);
    const float4 ad1 = *(const float4*)(a_dst + f1);
    float es = a0[0]*as0.x + a0[1]*as0.y + a0[2]*as0.z + a0[3]*as0.w
             + a1[0]*as1.x + a1[1]*as1.y + a1[2]*as1.z + a1[3]*as1.w;
    float ed = a0[0]*ad0.x + a0[1]*ad0.y + a0[2]*ad0.z + a0[3]*ad0.w
             + a1[0]*ad1.x + a1[1]*ad1.y + a1[2]*ad1.z + a1[3]*ad1.w;
#pragma unroll
    for (int off = 1; off < 16; off <<= 1) {
        es += __shfl_xor(es, off);
        ed += __shfl_xor(ed, off);
    }
    if (fg == 0) { esrc[t] = es; edst[t] = ed; }
}

// ------------- Kernel 2: attention + sentence (PV) + pool partials -------------
__global__ __launch_bounds__(256) void k_attn(
    const int* __restrict__ doc, const float* __restrict__ h,
    const float* __restrict__ esrc, const float* __restrict__ edst,
    float* __restrict__ out_att, float* __restrict__ out_sent,
    float* __restrict__ pool)
{
    __shared__ bf16  att[32][528];   // padded row stride (bank spread)
    __shared__ float edst_l[512];
    __shared__ float padv[512];      // 1 = valid (non-pad), 0 = pad
    __shared__ float esrc_l[32];
    __shared__ float rowv[32];

    const int tid = threadIdx.x;
    const int b   = blockIdx.y;
    const int rt  = blockIdx.x;      // 0..15
    const int i0  = rt * 32;

#pragma unroll
    for (int k = 0; k < 2; ++k) {
        int j = tid + k * 256;
        edst_l[j] = edst[b * NN + j];
        padv[j]   = (doc[b * NN + j] == PAD_ID) ? 0.f : 1.f;
    }
    if (tid < 32) {
        esrc_l[tid] = esrc[b * NN + i0 + tid];
        rowv[tid]   = (doc[b * NN + i0 + tid] == PAD_ID) ? 0.f : 1.f;
    }
    __syncthreads();

    const int wv   = tid >> 6;       // wave id 0..3
    const int lane = tid & 63;

    for (int r8 = 0; r8 < 8; ++r8) {
        const int il = (r8 << 2) + wv;          // local row 0..31
        const float es = esrc_l[il];
        const bool valid_row = rowv[il] != 0.f;

        float ev[8], vd[8];
        float m = -1e9f;
#pragma unroll
        for (int k = 0; k < 8; ++k) {
            int j = (k << 6) + lane;
            vd[k] = padv[j];
            float x = fmaxf(es + edst_l[j], 0.f);
            ev[k] = x;
            m = fmaxf(m, (vd[k] != 0.f) ? x : -1e9f);
        }
        m = wave_max(m);

        float p[8], s = 0.f;
#pragma unroll
        for (int k = 0; k < 8; ++k) {
            float pv = (vd[k] != 0.f) ? __expf(ev[k] - m) : 0.f;
            p[k] = pv; s += pv;
        }
        s = wave_sum(s);
        const float inv = valid_row ? (1.f / s) : 0.f;

        float* orow = out_att + ((size_t)b * NN + i0 + il) * NN;
#pragma unroll
        for (int k = 0; k < 8; ++k) {
            int j = (k << 6) + lane;
            float a = valid_row ? (p[k] * inv) : (1.f / 512.f);
            orow[j] = a;
            att[il][j] = __float2bfloat16(a);
        }
    }
    __syncthreads();

    // PV: sentence[i0..i0+32, :] = elu(att @ h[b])
    const int fg = tid & 31;         // 32 feature groups
    const int rg = tid >> 5;         // 8 row groups (4 rows each)
    const int f0 = fg << 2;
    const float* hb = h + (size_t)b * NN * NF + f0;

    float acc[4][4] = {};
    for (int j = 0; j < 512; ++j) {
        const float4 hv = *(const float4*)(hb + (size_t)j * NF);
#pragma unroll
        for (int r = 0; r < 4; ++r) {
            float a = __bfloat162float(att[(rg << 2) + r][j]);
            acc[r][0] = fmaf(a, hv.x, acc[r][0]);
            acc[r][1] = fmaf(a, hv.y, acc[r][1]);
            acc[r][2] = fmaf(a, hv.z, acc[r][2]);
            acc[r][3] = fmaf(a, hv.w, acc[r][3]);
        }
    }

    float ps[4] = {0.f,0.f,0.f,0.f};
#pragma unroll
    for (int r = 0; r < 4; ++r) {
        float4 o;
        o.x = acc[r][0] > 0.f ? acc[r][0] : expm1f(acc[r][0]);
        o.y = acc[r][1] > 0.f ? acc[r][1] : expm1f(acc[r][1]);
        o.z = acc[r][2] > 0.f ? acc[r][2] : expm1f(acc[r][2]);
        o.w = acc[r][3] > 0.f ? acc[r][3] : expm1f(acc[r][3]);
        *(float4*)(out_sent + ((size_t)b * NN + i0 + (rg << 2) + r) * NF + f0) = o;
        ps[0] += o.x; ps[1] += o.y; ps[2] += o.z; ps[3] += o.w;
    }
#pragma unroll
    for (int c = 0; c < 4; ++c)
        atomicAdd(&pool[b * NF + f0 + c], ps[c]);
}

// ---------------- Kernel 3: pool output + label softmax (axis=0) ----------------
__global__ __launch_bounds__(128) void k_label(
    const float* __restrict__ poolAccum, const float* __restrict__ Wc,
    const float* __restrict__ bc, float* __restrict__ out_pool,
    float* __restrict__ out_label)
{
    const int tid = threadIdx.x;
    for (int idx = tid; idx < NB * NF; idx += 128)
        out_pool[idx] = poolAccum[idx] * (1.f / 512.f);

    if (tid < 64) {
        const int b = tid;
        float z0 = bc[0], z1 = bc[1];
        for (int f = 0; f < NF; ++f) {
            float p = poolAccum[b * NF + f] * (1.f / 512.f);
            z0 = fmaf(p, Wc[f * 2 + 0], z0);
            z1 = fmaf(p, Wc[f * 2 + 1], z1);
        }
        float m0 = wave_max(z0), m1 = wave_max(z1);
        float e0 = __expf(z0 - m0), e1 = __expf(z1 - m1);
        float s0 = wave_sum(e0), s1 = wave_sum(e1);
        out_label[b * 2 + 0] = e0 / s0;
        out_label[b * 2 + 1] = e1 / s1;
    }
}

extern "C" void kernel_launch(void* const* d_in, const int* in_sizes, int n_in,
                              void* d_out, int out_size, void* d_ws, size_t ws_size,
                              hipStream_t stream)
{
    const int*   doc   = (const int*)d_in[0];
    const float* emb   = (const float*)d_in[1];
    const float* W     = (const float*)d_in[2];
    const float* a_src = (const float*)d_in[3];
    const float* a_dst = (const float*)d_in[4];
    const float* Wc    = (const float*)d_in[5];
    const float* bc    = (const float*)d_in[6];

    float* out       = (float*)d_out;
    float* out_pool  = out;                                    // 64*128
    float* out_att   = out_pool + NB * NF;                     // 64*512*512
    float* out_sent  = out_att + (size_t)NB * NN * NN;         // 64*512*128
    float* out_label = out_sent + (size_t)NB * NN * NF;        // 64*2

    float* h_ws  = (float*)d_ws;                               // 64*512*128 f32
    float* esrc  = h_ws + (size_t)NB * NN * NF;                // 64*512
    float* edst  = esrc + NB * NN;                             // 64*512
    float* pool  = edst + NB * NN;                             // 64*128 accum

    hipMemsetAsync(pool, 0, NB * NF * sizeof(float), stream);

    k_h<<<(NB * NN) / 16, 256, 0, stream>>>(doc, emb, W, a_src, a_dst, h_ws, esrc, edst);

    dim3 g2(16, NB);
    k_attn<<<g2, 256, 0, stream>>>(doc, h_ws, esrc, edst, out_att, out_sent, pool);

    k_label<<<1, 128, 0, stream>>>(pool, Wc, bc, out_pool, out_label);
}

// Round 5
// 182.680 us; speedup vs baseline: 1.5810x; 1.5810x over previous
//
#include <hip/hip_runtime.h>

#define NB 64
#define NN 512
#define ED 128
#define NF 128
#define PAD_ID 49999

typedef unsigned short ushort_t;
typedef __attribute__((ext_vector_type(8))) short short8v;
typedef __attribute__((ext_vector_type(4))) float f32x4;

__device__ __forceinline__ unsigned short f2b(float f) {
    unsigned int u = __float_as_uint(f);
    u = (u + 0x7fffu + ((u >> 16) & 1u)) >> 16;
    return (unsigned short)u;
}
__device__ __forceinline__ float b2f(unsigned short h) {
    return __uint_as_float(((unsigned int)h) << 16);
}

// ---------------- Kernel 1: h_T(bf16) = (emb[doc] @ W)^T, e_src, e_dst ----------------
// 512 blocks x 256 threads; block handles 64 tokens. Thread = 8 tokens x 4 feats.
__global__ __launch_bounds__(256) void k_h(
    const int* __restrict__ doc, const float* __restrict__ emb,
    const float* __restrict__ W, const float* __restrict__ a_src,
    const float* __restrict__ a_dst, ushort_t* __restrict__ hT,
    float* __restrict__ esrc, float* __restrict__ edst)
{
    __shared__ float wl[64][128];      // 32 KB gathered embeddings
    const int tid = threadIdx.x;
    const int t0  = blockIdx.x * 64;   // global token base (8 blocks per batch)
    const int b   = t0 >> 9;
    const int tl0 = t0 & (NN - 1);

    // gather: 64 tokens x 32 float4 = 2048 float4
#pragma unroll
    for (int k = 0; k < 8; ++k) {
        int idx = tid + k * 256;
        int tok = idx >> 5;
        int e4  = (idx & 31) << 2;
        int d   = doc[t0 + tok];
        *(float4*)&wl[tok][e4] = *(const float4*)(emb + (size_t)d * ED + e4);
    }
    __syncthreads();

    const int fg = tid & 31;  const int f0 = fg << 2;   // feats f0..f0+3
    const int tg = tid >> 5;                            // tokens tg*8..tg*8+7

    float acc[8][4] = {};
    for (int e = 0; e < 128; e += 4) {
        float4 wr[4];
#pragma unroll
        for (int k = 0; k < 4; ++k)
            wr[k] = *(const float4*)(W + (e + k) * NF + f0);
#pragma unroll
        for (int r = 0; r < 8; ++r) {
            const float4 x = *(const float4*)&wl[tg * 8 + r][e];
            const float xa[4] = {x.x, x.y, x.z, x.w};
#pragma unroll
            for (int k = 0; k < 4; ++k) {
                acc[r][0] = fmaf(xa[k], wr[k].x, acc[r][0]);
                acc[r][1] = fmaf(xa[k], wr[k].y, acc[r][1]);
                acc[r][2] = fmaf(xa[k], wr[k].z, acc[r][2]);
                acc[r][3] = fmaf(xa[k], wr[k].w, acc[r][3]);
            }
        }
    }

    // e_src / e_dst from exact f32 h (reduce across the 32 feature lanes)
    const float4 as = *(const float4*)(a_src + f0);
    const float4 ad = *(const float4*)(a_dst + f0);
#pragma unroll
    for (int r = 0; r < 8; ++r) {
        float es = acc[r][0]*as.x + acc[r][1]*as.y + acc[r][2]*as.z + acc[r][3]*as.w;
        float ed = acc[r][0]*ad.x + acc[r][1]*ad.y + acc[r][2]*ad.z + acc[r][3]*ad.w;
#pragma unroll
        for (int off = 1; off < 32; off <<= 1) {
            es += __shfl_xor(es, off);
            ed += __shfl_xor(ed, off);
        }
        if (fg == 0) {
            esrc[t0 + tg * 8 + r] = es;
            edst[t0 + tg * 8 + r] = ed;
        }
    }

    // write h_T bf16: [b][f][j], 8 consecutive tokens per 16B store
#pragma unroll
    for (int c = 0; c < 4; ++c) {
        union { ushort_t u[8]; uint4 v; } pk;
#pragma unroll
        for (int r = 0; r < 8; ++r) pk.u[r] = f2b(acc[r][c]);
        *(uint4*)(hT + (size_t)b * NF * NN + (size_t)(f0 + c) * NN + tl0 + tg * 8) = pk.v;
    }
}

// ------------- Kernel 2: attention (exact softmax) + MFMA PV + pool partials -------------
// grid (8, 64) x 256 threads; block = 64 att rows; wave w = 16 rows, all 128 feats.
__global__ __launch_bounds__(256) void k_attn(
    const int* __restrict__ doc, const ushort_t* __restrict__ hT,
    const float* __restrict__ esrc, const float* __restrict__ edst,
    float* __restrict__ out_att, float* __restrict__ out_sent,
    float* __restrict__ pool)
{
    __shared__ float edl[NN];
    __shared__ float pvl[NN];        // col valid: 1 / 0
    __shared__ float esl[64], rvl[64], invl[64];
    __shared__ float pool_l[NF];

    const int tid = threadIdx.x;
    const int b   = blockIdx.y;
    const int i0  = blockIdx.x * 64;

#pragma unroll
    for (int k = 0; k < 2; ++k) {
        int j = tid + k * 256;
        edl[j] = edst[b * NN + j];
        pvl[j] = (doc[b * NN + j] == PAD_ID) ? 0.f : 1.f;
    }
    if (tid < 64) {
        esl[tid] = esrc[b * NN + i0 + tid];
        rvl[tid] = (doc[b * NN + i0 + tid] == PAD_ID) ? 0.f : 1.f;
    }
    if (tid < NF) pool_l[tid] = 0.f;
    __syncthreads();

    const int w    = tid >> 6;
    const int lane = tid & 63;
    const int mr   = lane & 15;      // A-frag row within wave tile
    const int grp  = lane >> 4;      // k-group 0..3
    const int row_l = w * 16 + mr;   // block-local row
    const float es  = esl[row_l];
    const bool  rv  = rvl[row_l] != 0.f;

    // ---- pass 1: row max over valid cols ----
    float m = -1e30f;
#pragma unroll
    for (int ks = 0; ks < 16; ++ks) {
        const int j0 = ks * 32 + grp * 8;
        const float4 e0 = *(const float4*)&edl[j0], e1 = *(const float4*)&edl[j0 + 4];
        const float4 c0 = *(const float4*)&pvl[j0], c1 = *(const float4*)&pvl[j0 + 4];
        const float xs[8] = {es+e0.x, es+e0.y, es+e0.z, es+e0.w,
                             es+e1.x, es+e1.y, es+e1.z, es+e1.w};
        const float cs[8] = {c0.x, c0.y, c0.z, c0.w, c1.x, c1.y, c1.z, c1.w};
#pragma unroll
        for (int q = 0; q < 8; ++q) {
            const float x = fmaxf(xs[q], 0.f);
            m = fmaxf(m, cs[q] != 0.f ? x : -1e30f);
        }
    }
    m = fmaxf(m, __shfl_xor(m, 16));
    m = fmaxf(m, __shfl_xor(m, 32));

    // ---- pass 2: p = exp(x-m) (or 1 for all-pad rows), bf16 pack, sum ----
    float s = 0.f;
    unsigned int pb[64];             // 128 bf16 p-values: A-fragments for all K
#pragma unroll
    for (int ks = 0; ks < 16; ++ks) {
        const int j0 = ks * 32 + grp * 8;
        const float4 e0 = *(const float4*)&edl[j0], e1 = *(const float4*)&edl[j0 + 4];
        const float4 c0 = *(const float4*)&pvl[j0], c1 = *(const float4*)&pvl[j0 + 4];
        const float xs[8] = {es+e0.x, es+e0.y, es+e0.z, es+e0.w,
                             es+e1.x, es+e1.y, es+e1.z, es+e1.w};
        const float cs[8] = {c0.x, c0.y, c0.z, c0.w, c1.x, c1.y, c1.z, c1.w};
        float p[8];
#pragma unroll
        for (int q = 0; q < 8; ++q) {
            const float x = fmaxf(xs[q], 0.f);
            p[q] = rv ? (cs[q] != 0.f ? __expf(x - m) : 0.f) : 1.f;
            s += p[q];
        }
#pragma unroll
        for (int q = 0; q < 4; ++q)
            pb[ks * 4 + q] = ((unsigned)f2b(p[2*q+1]) << 16) | (unsigned)f2b(p[2*q]);
    }
    s += __shfl_xor(s, 16);
    s += __shfl_xor(s, 32);
    const float inv = rv ? (1.f / s) : (1.f / 512.f);
    if (grp == 0) invl[row_l] = inv;

    // ---- pass 3: write attention f32 ----
    float* arow = out_att + ((size_t)(b * NN + i0 + row_l)) * NN;
#pragma unroll
    for (int ks = 0; ks < 16; ++ks) {
        float4 o0, o1;
        o0.x = b2f((ushort_t)(pb[ks*4+0] & 0xffff)) * inv;
        o0.y = b2f((ushort_t)(pb[ks*4+0] >> 16))    * inv;
        o0.z = b2f((ushort_t)(pb[ks*4+1] & 0xffff)) * inv;
        o0.w = b2f((ushort_t)(pb[ks*4+1] >> 16))    * inv;
        o1.x = b2f((ushort_t)(pb[ks*4+2] & 0xffff)) * inv;
        o1.y = b2f((ushort_t)(pb[ks*4+2] >> 16))    * inv;
        o1.z = b2f((ushort_t)(pb[ks*4+3] & 0xffff)) * inv;
        o1.w = b2f((ushort_t)(pb[ks*4+3] >> 16))    * inv;
        *(float4*)(arow + ks * 32 + grp * 8)     = o0;
        *(float4*)(arow + ks * 32 + grp * 8 + 4) = o1;
    }
    __syncthreads();   // invl visible across lanes; pool_l zeroed

    // ---- PV: sentence = elu(inv * (p @ h)) via MFMA ----
    const ushort_t* hTb = hT + (size_t)b * NF * NN;
#pragma unroll
    for (int nt = 0; nt < 8; ++nt) {
        const int n0 = nt * 16;
        f32x4 acc = {0.f, 0.f, 0.f, 0.f};
        const ushort_t* bp = hTb + (size_t)(n0 + mr) * NN + grp * 8;
#pragma unroll
        for (int ks = 0; ks < 16; ++ks) {
            union { unsigned int u[4]; short8v v; } au;
            au.u[0] = pb[ks*4+0]; au.u[1] = pb[ks*4+1];
            au.u[2] = pb[ks*4+2]; au.u[3] = pb[ks*4+3];
            const short8v bv = *(const short8v*)(bp + ks * 32);
            acc = __builtin_amdgcn_mfma_f32_16x16x32_bf16(au.v, bv, acc, 0, 0, 0);
        }
        const int feat = n0 + mr;    // C/D: col = lane&15
        float psum = 0.f;
#pragma unroll
        for (int reg = 0; reg < 4; ++reg) {
            const int rl = w * 16 + grp * 4 + reg;   // C/D: row = (lane>>4)*4+reg
            float v = acc[reg] * invl[rl];
            v = v > 0.f ? v : expm1f(v);
            out_sent[((size_t)(b * NN + i0 + rl)) * NF + feat] = v;
            psum += v;
        }
        atomicAdd(&pool_l[feat], psum);
    }
    __syncthreads();
    if (tid < NF) atomicAdd(&pool[b * NF + tid], pool_l[tid]);
}

// ---------------- Kernel 3: pool output + label softmax (axis=0 = batch) ----------------
__global__ __launch_bounds__(128) void k_label(
    const float* __restrict__ poolAccum, const float* __restrict__ Wc,
    const float* __restrict__ bc, float* __restrict__ out_pool,
    float* __restrict__ out_label)
{
    const int tid = threadIdx.x;
    for (int i = tid; i < NB * NF / 4; i += 128) {
        float4 v = *(const float4*)(poolAccum + i * 4);
        v.x *= (1.f/512.f); v.y *= (1.f/512.f); v.z *= (1.f/512.f); v.w *= (1.f/512.f);
        *(float4*)(out_pool + i * 4) = v;
    }
    const int b = tid & 63, c = tid >> 6;    // wave 0: label 0, wave 1: label 1
    float z = bc[c];
    for (int f = 0; f < NF; ++f)
        z = fmaf(poolAccum[b * NF + f] * (1.f/512.f), Wc[f * 2 + c], z);
    float mz = z;
#pragma unroll
    for (int off = 32; off; off >>= 1) mz = fmaxf(mz, __shfl_xor(mz, off));
    float e = __expf(z - mz);
    float sv = e;
#pragma unroll
    for (int off = 32; off; off >>= 1) sv += __shfl_xor(sv, off);
    out_label[b * 2 + c] = e / sv;
}

extern "C" void kernel_launch(void* const* d_in, const int* in_sizes, int n_in,
                              void* d_out, int out_size, void* d_ws, size_t ws_size,
                              hipStream_t stream)
{
    const int*   doc   = (const int*)d_in[0];
    const float* emb   = (const float*)d_in[1];
    const float* W     = (const float*)d_in[2];
    const float* a_src = (const float*)d_in[3];
    const float* a_dst = (const float*)d_in[4];
    const float* Wc    = (const float*)d_in[5];
    const float* bc    = (const float*)d_in[6];

    float* out       = (float*)d_out;
    float* out_pool  = out;
    float* out_att   = out_pool + NB * NF;
    float* out_sent  = out_att + (size_t)NB * NN * NN;
    float* out_label = out_sent + (size_t)NB * NN * NF;

    char* base = (char*)d_ws;
    ushort_t* hT  = (ushort_t*)base;                              // 8 MB bf16
    float* esrc   = (float*)(base + (size_t)NB * NF * NN * 2);
    float* edst   = esrc + NB * NN;
    float* pool   = edst + NB * NN;

    hipMemsetAsync(pool, 0, NB * NF * sizeof(float), stream);

    k_h<<<(NB * NN) / 64, 256, 0, stream>>>(doc, emb, W, a_src, a_dst, hT, esrc, edst);

    dim3 g2(NN / 64, NB);
    k_attn<<<g2, 256, 0, stream>>>(doc, hT, esrc, edst, out_att, out_sent, pool);

    k_label<<<1, 128, 0, stream>>>(pool, Wc, bc, out_pool, out_label);
}